// Round 2
// baseline (1930.200 us; speedup 1.0000x reference)
//
#include <hip/hip_runtime.h>

// Problem constants
#define BB 256
#define SS 512
#define DD 128

__device__ __forceinline__ float sigf(float v)  { return 1.0f / (1.0f + __expf(-v)); }
__device__ __forceinline__ float tanhf_(float v){ return 1.0f - 2.0f / (__expf(2.0f * v) + 1.0f); }

// ---------------------------------------------------------------------------
// Kernel A: precompute additive tables (fold corr/qd/cd embedding matmul parts)
// ---------------------------------------------------------------------------
__global__ void dimkt_tables(const float* __restrict__ E_corr,
                             const float* __restrict__ E_qd,
                             const float* __restrict__ E_cd,
                             const float* __restrict__ W_ki,
                             const float* __restrict__ W_p1,
                             const float* __restrict__ W_p2,
                             const float* __restrict__ b_ki,
                             const float* __restrict__ b_p1,
                             const float* __restrict__ b_p2,
                             float* __restrict__ Ck, float* __restrict__ Cp1,
                             float* __restrict__ Cp2, float* __restrict__ Qk,
                             float* __restrict__ Cdk)
{
    __shared__ float e[128];
    const int r = blockIdx.x;
    const int j = threadIdx.x;
    const float *emb, *W, *bias;
    float* op;
    if (r < 2)        { emb = E_corr + r * 128;        W = W_ki + 128 * 128; bias = b_ki;    op = Ck  + r * 128; }
    else if (r < 4)   { emb = E_corr + (r - 2) * 128;  W = W_p1 + 128 * 128; bias = b_p1;    op = Cp1 + (r - 2) * 128; }
    else if (r < 6)   { emb = E_corr + (r - 4) * 128;  W = W_p2 + 128 * 128; bias = b_p2;    op = Cp2 + (r - 4) * 128; }
    else if (r < 107) { emb = E_qd   + (r - 6) * 128;  W = W_ki + 256 * 128; bias = nullptr; op = Qk  + (r - 6) * 128; }
    else              { emb = E_cd   + (r - 107) * 128; W = W_ki + 384 * 128; bias = nullptr; op = Cdk + (r - 107) * 128; }
    e[j] = emb[j];
    __syncthreads();
    float acc = bias ? bias[j] : 0.0f;
#pragma unroll 8
    for (int i = 0; i < 128; ++i) acc = fmaf(e[i], W[i * 128 + j], acc);
    op[j] = acc;
}

// ---------------------------------------------------------------------------
// Kernel B: x = concat(E_q[q], E_c[c], E_qd[qd], E_cd[cd]) @ Wx + bx
//   (unchanged from round 1 — fp32 LDS-tiled GEMM; MFMA candidate next round)
// ---------------------------------------------------------------------------
#define AP 134

__global__ __launch_bounds__(256, 2) void dimkt_xgemm(
    const int* __restrict__ q_seq, const int* __restrict__ c_seq,
    const int* __restrict__ qd_seq, const int* __restrict__ cd_seq,
    const float* __restrict__ E_q, const float* __restrict__ E_c,
    const float* __restrict__ E_qd, const float* __restrict__ E_cd,
    const float* __restrict__ Wx, const float* __restrict__ bx,
    float* __restrict__ xout)
{
    __shared__ float As[128 * AP];
    __shared__ float Bs[128 * 128];
    const int tid = threadIdx.x;
    const int ty = tid >> 4;
    const int tx = tid & 15;
    const int m0 = blockIdx.x * 128;

    const int*   seqs[4] = { q_seq, c_seq, qd_seq, cd_seq };
    const float* tabs[4] = { E_q,   E_c,   E_qd,   E_cd  };

    float acc[8][8];
#pragma unroll
    for (int r = 0; r < 8; ++r)
#pragma unroll
        for (int c = 0; c < 8; ++c) acc[r][c] = 0.0f;

#pragma unroll 1
    for (int s = 0; s < 4; ++s) {
        __syncthreads();
        const int*   sq = seqs[s];
        const float* tb = tabs[s];
        for (int i = tid; i < 128 * 64; i += 256) {
            int row = i >> 6;
            int c2  = (i & 63) << 1;
            int e   = sq[m0 + row];
            float2 v = *(const float2*)&tb[e * 128 + c2];
            *(float2*)&As[row * AP + c2] = v;
        }
        for (int i = tid; i < 128 * 32; i += 256) {
            int k  = i >> 5;
            int c4 = (i & 31) << 2;
            *(float4*)&Bs[k * 128 + c4] = *(const float4*)&Wx[(s * 128 + k) * 128 + c4];
        }
        __syncthreads();
#pragma unroll 4
        for (int k = 0; k < 128; ++k) {
            float a[8];
#pragma unroll
            for (int r = 0; r < 8; ++r) a[r] = As[(ty * 8 + r) * AP + k];
            float4 b0 = *(const float4*)&Bs[k * 128 + tx * 8];
            float4 b1 = *(const float4*)&Bs[k * 128 + tx * 8 + 4];
            float bb[8] = { b0.x, b0.y, b0.z, b0.w, b1.x, b1.y, b1.z, b1.w };
#pragma unroll
            for (int r = 0; r < 8; ++r)
#pragma unroll
                for (int c = 0; c < 8; ++c)
                    acc[r][c] = fmaf(a[r], bb[c], acc[r][c]);
        }
    }

    float4 bx0 = *(const float4*)&bx[tx * 8];
    float4 bx1 = *(const float4*)&bx[tx * 8 + 4];
    float bxa[8] = { bx0.x, bx0.y, bx0.z, bx0.w, bx1.x, bx1.y, bx1.z, bx1.w };
#pragma unroll
    for (int r = 0; r < 8; ++r) {
        int row = m0 + ty * 8 + r;
        float4 o0 = make_float4(acc[r][0] + bxa[0], acc[r][1] + bxa[1],
                                acc[r][2] + bxa[2], acc[r][3] + bxa[3]);
        float4 o1 = make_float4(acc[r][4] + bxa[4], acc[r][5] + bxa[5],
                                acc[r][6] + bxa[6], acc[r][7] + bxa[7]);
        *(float4*)&xout[row * 128 + tx * 8]     = o0;
        *(float4*)&xout[row * 128 + tx * 8 + 4] = o1;
    }
}

// ---------------------------------------------------------------------------
// Kernel C: sequential scan, restructured.
//   512 threads (8 waves, 2/SIMD) per batch element. Thread (rg=tid>>7,
//   j=tid&127) owns rows [32rg,32rg+32) of column j for all 5 matrices:
//   160 weight floats/thread -> fits the 256-VGPR cap of launch_bounds(512,2),
//   guaranteeing register residence (round-1 failure: 320/thread spilled).
//   4 barriers/step; reduce stages role-split across waves; all global loads
//   (tables, x_{t+1}) prefetched ~1 step ahead.
// ---------------------------------------------------------------------------
__global__ __launch_bounds__(512, 2) void dimkt_scan(
    const float* __restrict__ x,
    const int* __restrict__ corr_seq, const int* __restrict__ qd_seq,
    const int* __restrict__ cd_seq,
    const float* __restrict__ W_s1, const float* __restrict__ b_s1,
    const float* __restrict__ W_s2, const float* __restrict__ b_s2,
    const float* __restrict__ W_p1, const float* __restrict__ W_p2,
    const float* __restrict__ W_ki,
    const float* __restrict__ Ck, const float* __restrict__ Cp1,
    const float* __restrict__ Cp2, const float* __restrict__ Qk,
    const float* __restrict__ Cdk,
    const float* __restrict__ h0, float* __restrict__ out)
{
    __shared__ float h_lds[128], d_lds[128], sdf_lds[128], g_lds[128];
    __shared__ float xn_lds[128], prod_lds[128];
    __shared__ float pA1[4][128], pA2[4][128], pKG[4][128], pP1[4][128], pP2[4][128];

    const int tid  = threadIdx.x;
    const int b    = blockIdx.x;
    const int j    = tid & 127;      // column
    const int rg   = tid >> 7;       // row group (32 rows); uniform per wave
    const int base = b * SS;

    // --- register-resident weights: rows [32rg, 32rg+32), column j ----------
    float w1[32], w2[32], wk[32], wp1[32], wp2[32];
#pragma unroll 8
    for (int k = 0; k < 32; ++k) {
        const int idx = (rg * 32 + k) * 128 + j;
        w1[k]  = W_s1[idx];
        w2[k]  = W_s2[idx];
        wk[k]  = W_ki[idx];
        wp1[k] = W_p1[idx];
        wp2[k] = W_p2[idx];
    }

    float bs1 = 0.f, bs2 = 0.f;
    float tCk = 0.f, tQk = 0.f, tCdk = 0.f, tCp1 = 0.f, tCp2 = 0.f;

    // --- init: h_0, d_0 = x_0 - h_0, step-0 tables --------------------------
    if (tid < 128) {
        bs1 = b_s1[j];
        bs2 = b_s2[j];
        float hv = h0[b * 128 + j];
        float xv = x[(size_t)base * 128 + j];
        h_lds[j] = hv;
        d_lds[j] = xv - hv;
        int c0 = corr_seq[base];
        tCp1 = Cp1[c0 * 128 + j];
        tCp2 = Cp2[c0 * 128 + j];
    } else if (tid < 256) {
        int c0 = corr_seq[base], q0 = qd_seq[base], e0 = cd_seq[base];
        tCk  = Ck [c0 * 128 + j];
        tQk  = Qk [q0 * 128 + j];
        tCdk = Cdk[e0 * 128 + j];
    }
    __syncthreads();

    for (int t = 0; t < 511; ++t) {
        // ---- P1: phase-1 matvec partials (all 512 threads) ----------------
        {
            float a1p = 0.f, a2p = 0.f, kgp = 0.f;
#pragma unroll
            for (int c = 0; c < 4; ++c) {
                const int k8 = c * 8;
                float4 da = *(const float4*)&d_lds[rg * 32 + k8];
                float4 db = *(const float4*)&d_lds[rg * 32 + k8 + 4];
                float4 ha = *(const float4*)&h_lds[rg * 32 + k8];
                float4 hb = *(const float4*)&h_lds[rg * 32 + k8 + 4];
                a1p = fmaf(da.x, w1[k8+0], a1p); a2p = fmaf(da.x, w2[k8+0], a2p); kgp = fmaf(ha.x, wk[k8+0], kgp);
                a1p = fmaf(da.y, w1[k8+1], a1p); a2p = fmaf(da.y, w2[k8+1], a2p); kgp = fmaf(ha.y, wk[k8+1], kgp);
                a1p = fmaf(da.z, w1[k8+2], a1p); a2p = fmaf(da.z, w2[k8+2], a2p); kgp = fmaf(ha.z, wk[k8+2], kgp);
                a1p = fmaf(da.w, w1[k8+3], a1p); a2p = fmaf(da.w, w2[k8+3], a2p); kgp = fmaf(ha.w, wk[k8+3], kgp);
                a1p = fmaf(db.x, w1[k8+4], a1p); a2p = fmaf(db.x, w2[k8+4], a2p); kgp = fmaf(hb.x, wk[k8+4], kgp);
                a1p = fmaf(db.y, w1[k8+5], a1p); a2p = fmaf(db.y, w2[k8+5], a2p); kgp = fmaf(hb.y, wk[k8+5], kgp);
                a1p = fmaf(db.z, w1[k8+6], a1p); a2p = fmaf(db.z, w2[k8+6], a2p); kgp = fmaf(hb.z, wk[k8+6], kgp);
                a1p = fmaf(db.w, w1[k8+7], a1p); a2p = fmaf(db.w, w2[k8+7], a2p); kgp = fmaf(hb.w, wk[k8+7], kgp);
            }
            pA1[rg][j] = a1p;
            pA2[rg][j] = a2p;
            pKG[rg][j] = kgp;
        }
        __syncthreads();   // B1

        // ---- P2: role-split reduce / prefetch -----------------------------
        if (tid < 128) {
            // sdf (critical path)
            float a1 = pA1[0][j] + pA1[1][j] + pA1[2][j] + pA1[3][j] + bs1;
            float a2 = pA2[0][j] + pA2[1][j] + pA2[2][j] + pA2[3][j] + bs2;
            sdf_lds[j] = sigf(a1) * tanhf_(a2);
        } else if (tid < 256) {
            // gate g + next-step ki-table prefetch
            float kg = pKG[0][j] + pKG[1][j] + pKG[2][j] + pKG[3][j]
                     + tCk + tQk + tCdk;
            g_lds[j] = sigf(kg);
            int nt = base + t + 1;
            int c1 = corr_seq[nt], q1 = qd_seq[nt], e1 = cd_seq[nt];
            tCk  = Ck [c1 * 128 + j];
            tQk  = Qk [q1 * 128 + j];
            tCdk = Cdk[e1 * 128 + j];
        } else if (tid < 320) {
            // y_{t-1} = sigmoid(x_t . h_t) from prod_lds written at P4(t-1)
            if (t > 0) {
                int lane = tid - 256;
                float2 pv = *(const float2*)&prod_lds[lane * 2];
                float s = pv.x + pv.y;
#pragma unroll
                for (int m = 32; m; m >>= 1) s += __shfl_xor(s, m);
                if (lane == 0) out[base + t - 1] = sigf(s);
            }
        } else if (tid < 448) {
            // prefetch x_{t+1} into LDS (consumed at P4)
            int jj = tid - 320;
            xn_lds[jj] = x[(size_t)(base + t + 1) * 128 + jj];
        }
        __syncthreads();   // B2

        // ---- P3: phase-2 matvec partials (all 512 threads) ----------------
        {
            float p1p = 0.f, p2p = 0.f;
#pragma unroll
            for (int c = 0; c < 4; ++c) {
                const int k8 = c * 8;
                float4 sa = *(const float4*)&sdf_lds[rg * 32 + k8];
                float4 sb = *(const float4*)&sdf_lds[rg * 32 + k8 + 4];
                p1p = fmaf(sa.x, wp1[k8+0], p1p); p2p = fmaf(sa.x, wp2[k8+0], p2p);
                p1p = fmaf(sa.y, wp1[k8+1], p1p); p2p = fmaf(sa.y, wp2[k8+1], p2p);
                p1p = fmaf(sa.z, wp1[k8+2], p1p); p2p = fmaf(sa.z, wp2[k8+2], p2p);
                p1p = fmaf(sa.w, wp1[k8+3], p1p); p2p = fmaf(sa.w, wp2[k8+3], p2p);
                p1p = fmaf(sb.x, wp1[k8+4], p1p); p2p = fmaf(sb.x, wp2[k8+4], p2p);
                p1p = fmaf(sb.y, wp1[k8+5], p1p); p2p = fmaf(sb.y, wp2[k8+5], p2p);
                p1p = fmaf(sb.z, wp1[k8+6], p1p); p2p = fmaf(sb.z, wp2[k8+6], p2p);
                p1p = fmaf(sb.w, wp1[k8+7], p1p); p2p = fmaf(sb.w, wp2[k8+7], p2p);
            }
            pP1[rg][j] = p1p;
            pP2[rg][j] = p2p;
        }
        __syncthreads();   // B3

        // ---- P4: reduce phase-2, h update, d/prod for next step -----------
        if (tid < 128) {
            float p1 = pP1[0][j] + pP1[1][j] + pP1[2][j] + pP1[3][j] + tCp1;
            float p2 = pP2[0][j] + pP2[1][j] + pP2[2][j] + pP2[3][j] + tCp2;
            float pka = sigf(p1) * tanhf_(p2);
            float g  = g_lds[j];
            float hv = h_lds[j];
            float hn = g * hv + (1.0f - g) * pka;
            float xv = xn_lds[j];            // x_{t+1}
            h_lds[j]    = hn;
            d_lds[j]    = xv - hn;
            prod_lds[j] = xv * hn;           // y_t product
            int c1 = corr_seq[base + t + 1];
            tCp1 = Cp1[c1 * 128 + j];
            tCp2 = Cp2[c1 * 128 + j];
        }
        __syncthreads();   // B4
    }

    // ---- epilogue: y_510; y[:,511] = 0 -------------------------------------
    if (tid < 64) {
        float2 pv = *(const float2*)&prod_lds[tid * 2];
        float s = pv.x + pv.y;
#pragma unroll
        for (int m = 32; m; m >>= 1) s += __shfl_xor(s, m);
        if (tid == 0) out[base + 510] = sigf(s);
    }
    if (tid == 0) out[base + 511] = 0.0f;
}

// ---------------------------------------------------------------------------
extern "C" void kernel_launch(void* const* d_in, const int* in_sizes, int n_in,
                              void* d_out, int out_size, void* d_ws, size_t ws_size,
                              hipStream_t stream) {
    const int*   q_seq    = (const int*)d_in[0];
    const int*   c_seq    = (const int*)d_in[1];
    const int*   qd_seq   = (const int*)d_in[2];
    const int*   cd_seq   = (const int*)d_in[3];
    const int*   corr_seq = (const int*)d_in[4];
    const float* E_q    = (const float*)d_in[5];
    const float* E_c    = (const float*)d_in[6];
    const float* E_qd   = (const float*)d_in[7];
    const float* E_cd   = (const float*)d_in[8];
    const float* E_corr = (const float*)d_in[9];
    const float* Wx     = (const float*)d_in[10];
    const float* bx     = (const float*)d_in[11];
    const float* W_s1   = (const float*)d_in[12];
    const float* b_s1   = (const float*)d_in[13];
    const float* W_s2   = (const float*)d_in[14];
    const float* b_s2   = (const float*)d_in[15];
    const float* W_p1   = (const float*)d_in[16];
    const float* b_p1   = (const float*)d_in[17];
    const float* W_p2   = (const float*)d_in[18];
    const float* b_p2   = (const float*)d_in[19];
    const float* W_ki   = (const float*)d_in[20];
    const float* b_ki   = (const float*)d_in[21];
    const float* h0     = (const float*)d_in[22];
    float* out = (float*)d_out;

    float* xbuf = (float*)d_ws;
    float* Ck   = xbuf + (size_t)BB * SS * DD;
    float* Cp1  = Ck  + 256;
    float* Cp2  = Cp1 + 256;
    float* Qk   = Cp2 + 256;
    float* Cdk  = Qk  + 101 * 128;

    dimkt_tables<<<208, 128, 0, stream>>>(E_corr, E_qd, E_cd, W_ki, W_p1, W_p2,
                                          b_ki, b_p1, b_p2, Ck, Cp1, Cp2, Qk, Cdk);

    dimkt_xgemm<<<(BB * SS) / 128, 256, 0, stream>>>(q_seq, c_seq, qd_seq, cd_seq,
                                                     E_q, E_c, E_qd, E_cd, Wx, bx, xbuf);

    dimkt_scan<<<BB, 512, 0, stream>>>(xbuf, corr_seq, qd_seq, cd_seq,
                                       W_s1, b_s1, W_s2, b_s2, W_p1, W_p2, W_ki,
                                       Ck, Cp1, Cp2, Qk, Cdk, h0, out);
}

// Round 3
// 1094.063 us; speedup vs baseline: 1.7642x; 1.7642x over previous
//
#include <hip/hip_runtime.h>

// Problem constants
#define BB 256
#define SS 512
#define DD 128

__device__ __forceinline__ float sigf(float v)  { return 1.0f / (1.0f + __expf(-v)); }
__device__ __forceinline__ float tanhf_(float v){ return 1.0f - 2.0f / (__expf(2.0f * v) + 1.0f); }

// ---------------------------------------------------------------------------
// Kernel A: precompute additive tables (fold corr/qd/cd embedding matmul parts)
// ---------------------------------------------------------------------------
__global__ void dimkt_tables(const float* __restrict__ E_corr,
                             const float* __restrict__ E_qd,
                             const float* __restrict__ E_cd,
                             const float* __restrict__ W_ki,
                             const float* __restrict__ W_p1,
                             const float* __restrict__ W_p2,
                             const float* __restrict__ b_ki,
                             const float* __restrict__ b_p1,
                             const float* __restrict__ b_p2,
                             float* __restrict__ Ck, float* __restrict__ Cp1,
                             float* __restrict__ Cp2, float* __restrict__ Qk,
                             float* __restrict__ Cdk)
{
    __shared__ float e[128];
    const int r = blockIdx.x;
    const int j = threadIdx.x;
    const float *emb, *W, *bias;
    float* op;
    if (r < 2)        { emb = E_corr + r * 128;        W = W_ki + 128 * 128; bias = b_ki;    op = Ck  + r * 128; }
    else if (r < 4)   { emb = E_corr + (r - 2) * 128;  W = W_p1 + 128 * 128; bias = b_p1;    op = Cp1 + (r - 2) * 128; }
    else if (r < 6)   { emb = E_corr + (r - 4) * 128;  W = W_p2 + 128 * 128; bias = b_p2;    op = Cp2 + (r - 4) * 128; }
    else if (r < 107) { emb = E_qd   + (r - 6) * 128;  W = W_ki + 256 * 128; bias = nullptr; op = Qk  + (r - 6) * 128; }
    else              { emb = E_cd   + (r - 107) * 128; W = W_ki + 384 * 128; bias = nullptr; op = Cdk + (r - 107) * 128; }
    e[j] = emb[j];
    __syncthreads();
    float acc = bias ? bias[j] : 0.0f;
#pragma unroll 8
    for (int i = 0; i < 128; ++i) acc = fmaf(e[i], W[i * 128 + j], acc);
    op[j] = acc;
}

// ---------------------------------------------------------------------------
// Kernel B: x = concat(E_q[q], E_c[c], E_qd[qd], E_cd[cd]) @ Wx + bx
//   (unchanged — fp32 LDS-tiled GEMM; MFMA candidate next round)
// ---------------------------------------------------------------------------
#define AP 134

__global__ __launch_bounds__(256, 2) void dimkt_xgemm(
    const int* __restrict__ q_seq, const int* __restrict__ c_seq,
    const int* __restrict__ qd_seq, const int* __restrict__ cd_seq,
    const float* __restrict__ E_q, const float* __restrict__ E_c,
    const float* __restrict__ E_qd, const float* __restrict__ E_cd,
    const float* __restrict__ Wx, const float* __restrict__ bx,
    float* __restrict__ xout)
{
    __shared__ float As[128 * AP];
    __shared__ float Bs[128 * 128];
    const int tid = threadIdx.x;
    const int ty = tid >> 4;
    const int tx = tid & 15;
    const int m0 = blockIdx.x * 128;

    const int*   seqs[4] = { q_seq, c_seq, qd_seq, cd_seq };
    const float* tabs[4] = { E_q,   E_c,   E_qd,   E_cd  };

    float acc[8][8];
#pragma unroll
    for (int r = 0; r < 8; ++r)
#pragma unroll
        for (int c = 0; c < 8; ++c) acc[r][c] = 0.0f;

#pragma unroll 1
    for (int s = 0; s < 4; ++s) {
        __syncthreads();
        const int*   sq = seqs[s];
        const float* tb = tabs[s];
        for (int i = tid; i < 128 * 64; i += 256) {
            int row = i >> 6;
            int c2  = (i & 63) << 1;
            int e   = sq[m0 + row];
            float2 v = *(const float2*)&tb[e * 128 + c2];
            *(float2*)&As[row * AP + c2] = v;
        }
        for (int i = tid; i < 128 * 32; i += 256) {
            int k  = i >> 5;
            int c4 = (i & 31) << 2;
            *(float4*)&Bs[k * 128 + c4] = *(const float4*)&Wx[(s * 128 + k) * 128 + c4];
        }
        __syncthreads();
#pragma unroll 4
        for (int k = 0; k < 128; ++k) {
            float a[8];
#pragma unroll
            for (int r = 0; r < 8; ++r) a[r] = As[(ty * 8 + r) * AP + k];
            float4 b0 = *(const float4*)&Bs[k * 128 + tx * 8];
            float4 b1 = *(const float4*)&Bs[k * 128 + tx * 8 + 4];
            float bb[8] = { b0.x, b0.y, b0.z, b0.w, b1.x, b1.y, b1.z, b1.w };
#pragma unroll
            for (int r = 0; r < 8; ++r)
#pragma unroll
                for (int c = 0; c < 8; ++c)
                    acc[r][c] = fmaf(a[r], bb[c], acc[r][c]);
        }
    }

    float4 bx0 = *(const float4*)&bx[tx * 8];
    float4 bx1 = *(const float4*)&bx[tx * 8 + 4];
    float bxa[8] = { bx0.x, bx0.y, bx0.z, bx0.w, bx1.x, bx1.y, bx1.z, bx1.w };
#pragma unroll
    for (int r = 0; r < 8; ++r) {
        int row = m0 + ty * 8 + r;
        float4 o0 = make_float4(acc[r][0] + bxa[0], acc[r][1] + bxa[1],
                                acc[r][2] + bxa[2], acc[r][3] + bxa[3]);
        float4 o1 = make_float4(acc[r][4] + bxa[4], acc[r][5] + bxa[5],
                                acc[r][6] + bxa[6], acc[r][7] + bxa[7]);
        *(float4*)&xout[row * 128 + tx * 8]     = o0;
        *(float4*)&xout[row * 128 + tx * 8 + 4] = o1;
    }
}

// ---------------------------------------------------------------------------
// Kernel C: sequential scan (round-2 structure, spill bug fixed).
//   512 threads (8 waves, 2/SIMD) per batch element. Thread (rg=tid>>7,
//   j=tid&127) owns rows [32rg,32rg+32) of column j for all 5 matrices.
//   CRITICAL (guide rule #20): the weight-load loop must be FULLY unrolled so
//   every w*[k] access has a compile-time index; round 2's "#pragma unroll 8"
//   left runtime indices -> all 160 floats/thread went to scratch
//   (VGPR_Count=124, WRITE_SIZE 23 MB of spill traffic).
// ---------------------------------------------------------------------------
__global__ __launch_bounds__(512, 2) void dimkt_scan(
    const float* __restrict__ x,
    const int* __restrict__ corr_seq, const int* __restrict__ qd_seq,
    const int* __restrict__ cd_seq,
    const float* __restrict__ W_s1, const float* __restrict__ b_s1,
    const float* __restrict__ W_s2, const float* __restrict__ b_s2,
    const float* __restrict__ W_p1, const float* __restrict__ W_p2,
    const float* __restrict__ W_ki,
    const float* __restrict__ Ck, const float* __restrict__ Cp1,
    const float* __restrict__ Cp2, const float* __restrict__ Qk,
    const float* __restrict__ Cdk,
    const float* __restrict__ h0, float* __restrict__ out)
{
    __shared__ float h_lds[128], d_lds[128], sdf_lds[128], g_lds[128];
    __shared__ float xn_lds[128], prod_lds[128];
    __shared__ float pA1[4][128], pA2[4][128], pKG[4][128], pP1[4][128], pP2[4][128];

    const int tid  = threadIdx.x;
    const int b    = blockIdx.x;
    const int j    = tid & 127;      // column
    const int rg   = tid >> 7;       // row group (32 rows); uniform per wave
    const int base = b * SS;

    // --- register-resident weights: rows [32rg, 32rg+32), column j ----------
    // FULL unroll: compile-time indices -> arrays promoted to VGPRs.
    float w1[32], w2[32], wk[32], wp1[32], wp2[32];
    {
        const float* ws1 = W_s1 + (rg * 32) * 128 + j;
        const float* ws2 = W_s2 + (rg * 32) * 128 + j;
        const float* wki = W_ki + (rg * 32) * 128 + j;
        const float* wpa = W_p1 + (rg * 32) * 128 + j;
        const float* wpb = W_p2 + (rg * 32) * 128 + j;
#pragma unroll
        for (int k = 0; k < 32; ++k) {
            w1[k]  = ws1[k * 128];
            w2[k]  = ws2[k * 128];
            wk[k]  = wki[k * 128];
            wp1[k] = wpa[k * 128];
            wp2[k] = wpb[k * 128];
        }
    }

    float bs1 = 0.f, bs2 = 0.f;
    float tCk = 0.f, tQk = 0.f, tCdk = 0.f, tCp1 = 0.f, tCp2 = 0.f;

    // --- init: h_0, d_0 = x_0 - h_0, step-0 tables --------------------------
    if (tid < 128) {
        bs1 = b_s1[j];
        bs2 = b_s2[j];
        float hv = h0[b * 128 + j];
        float xv = x[(size_t)base * 128 + j];
        h_lds[j] = hv;
        d_lds[j] = xv - hv;
        int c0 = corr_seq[base];
        tCp1 = Cp1[c0 * 128 + j];
        tCp2 = Cp2[c0 * 128 + j];
    } else if (tid < 256) {
        int c0 = corr_seq[base], q0 = qd_seq[base], e0 = cd_seq[base];
        tCk  = Ck [c0 * 128 + j];
        tQk  = Qk [q0 * 128 + j];
        tCdk = Cdk[e0 * 128 + j];
    }
    __syncthreads();

    for (int t = 0; t < 511; ++t) {
        // ---- P1: phase-1 matvec partials (all 512 threads) ----------------
        {
            float a1p = 0.f, a2p = 0.f, kgp = 0.f;
#pragma unroll
            for (int c = 0; c < 4; ++c) {
                const int k8 = c * 8;
                float4 da = *(const float4*)&d_lds[rg * 32 + k8];
                float4 db = *(const float4*)&d_lds[rg * 32 + k8 + 4];
                float4 ha = *(const float4*)&h_lds[rg * 32 + k8];
                float4 hb = *(const float4*)&h_lds[rg * 32 + k8 + 4];
                a1p = fmaf(da.x, w1[k8+0], a1p); a2p = fmaf(da.x, w2[k8+0], a2p); kgp = fmaf(ha.x, wk[k8+0], kgp);
                a1p = fmaf(da.y, w1[k8+1], a1p); a2p = fmaf(da.y, w2[k8+1], a2p); kgp = fmaf(ha.y, wk[k8+1], kgp);
                a1p = fmaf(da.z, w1[k8+2], a1p); a2p = fmaf(da.z, w2[k8+2], a2p); kgp = fmaf(ha.z, wk[k8+2], kgp);
                a1p = fmaf(da.w, w1[k8+3], a1p); a2p = fmaf(da.w, w2[k8+3], a2p); kgp = fmaf(ha.w, wk[k8+3], kgp);
                a1p = fmaf(db.x, w1[k8+4], a1p); a2p = fmaf(db.x, w2[k8+4], a2p); kgp = fmaf(hb.x, wk[k8+4], kgp);
                a1p = fmaf(db.y, w1[k8+5], a1p); a2p = fmaf(db.y, w2[k8+5], a2p); kgp = fmaf(hb.y, wk[k8+5], kgp);
                a1p = fmaf(db.z, w1[k8+6], a1p); a2p = fmaf(db.z, w2[k8+6], a2p); kgp = fmaf(hb.z, wk[k8+6], kgp);
                a1p = fmaf(db.w, w1[k8+7], a1p); a2p = fmaf(db.w, w2[k8+7], a2p); kgp = fmaf(hb.w, wk[k8+7], kgp);
            }
            pA1[rg][j] = a1p;
            pA2[rg][j] = a2p;
            pKG[rg][j] = kgp;
        }
        __syncthreads();   // B1

        // ---- P2: role-split reduce / prefetch -----------------------------
        if (tid < 128) {
            // sdf (critical path)
            float a1 = pA1[0][j] + pA1[1][j] + pA1[2][j] + pA1[3][j] + bs1;
            float a2 = pA2[0][j] + pA2[1][j] + pA2[2][j] + pA2[3][j] + bs2;
            sdf_lds[j] = sigf(a1) * tanhf_(a2);
        } else if (tid < 256) {
            // gate g + next-step ki-table prefetch
            float kg = pKG[0][j] + pKG[1][j] + pKG[2][j] + pKG[3][j]
                     + tCk + tQk + tCdk;
            g_lds[j] = sigf(kg);
            int nt = base + t + 1;
            int c1 = corr_seq[nt], q1 = qd_seq[nt], e1 = cd_seq[nt];
            tCk  = Ck [c1 * 128 + j];
            tQk  = Qk [q1 * 128 + j];
            tCdk = Cdk[e1 * 128 + j];
        } else if (tid < 320) {
            // y_{t-1} = sigmoid(x_t . h_t) from prod_lds written at P4(t-1)
            if (t > 0) {
                int lane = tid - 256;
                float2 pv = *(const float2*)&prod_lds[lane * 2];
                float s = pv.x + pv.y;
#pragma unroll
                for (int m = 32; m; m >>= 1) s += __shfl_xor(s, m);
                if (lane == 0) out[base + t - 1] = sigf(s);
            }
        } else if (tid < 448) {
            // prefetch x_{t+1} into LDS (consumed at P4)
            int jj = tid - 320;
            xn_lds[jj] = x[(size_t)(base + t + 1) * 128 + jj];
        }
        __syncthreads();   // B2

        // ---- P3: phase-2 matvec partials (all 512 threads) ----------------
        {
            float p1p = 0.f, p2p = 0.f;
#pragma unroll
            for (int c = 0; c < 4; ++c) {
                const int k8 = c * 8;
                float4 sa = *(const float4*)&sdf_lds[rg * 32 + k8];
                float4 sb = *(const float4*)&sdf_lds[rg * 32 + k8 + 4];
                p1p = fmaf(sa.x, wp1[k8+0], p1p); p2p = fmaf(sa.x, wp2[k8+0], p2p);
                p1p = fmaf(sa.y, wp1[k8+1], p1p); p2p = fmaf(sa.y, wp2[k8+1], p2p);
                p1p = fmaf(sa.z, wp1[k8+2], p1p); p2p = fmaf(sa.z, wp2[k8+2], p2p);
                p1p = fmaf(sa.w, wp1[k8+3], p1p); p2p = fmaf(sa.w, wp2[k8+3], p2p);
                p1p = fmaf(sb.x, wp1[k8+4], p1p); p2p = fmaf(sb.x, wp2[k8+4], p2p);
                p1p = fmaf(sb.y, wp1[k8+5], p1p); p2p = fmaf(sb.y, wp2[k8+5], p2p);
                p1p = fmaf(sb.z, wp1[k8+6], p1p); p2p = fmaf(sb.z, wp2[k8+6], p2p);
                p1p = fmaf(sb.w, wp1[k8+7], p1p); p2p = fmaf(sb.w, wp2[k8+7], p2p);
            }
            pP1[rg][j] = p1p;
            pP2[rg][j] = p2p;
        }
        __syncthreads();   // B3

        // ---- P4: reduce phase-2, h update, d/prod for next step -----------
        if (tid < 128) {
            float p1 = pP1[0][j] + pP1[1][j] + pP1[2][j] + pP1[3][j] + tCp1;
            float p2 = pP2[0][j] + pP2[1][j] + pP2[2][j] + pP2[3][j] + tCp2;
            float pka = sigf(p1) * tanhf_(p2);
            float g  = g_lds[j];
            float hv = h_lds[j];
            float hn = g * hv + (1.0f - g) * pka;
            float xv = xn_lds[j];            // x_{t+1}
            h_lds[j]    = hn;
            d_lds[j]    = xv - hn;
            prod_lds[j] = xv * hn;           // y_t product
            int c1 = corr_seq[base + t + 1];
            tCp1 = Cp1[c1 * 128 + j];
            tCp2 = Cp2[c1 * 128 + j];
        }
        __syncthreads();   // B4
    }

    // ---- epilogue: y_510; y[:,511] = 0 -------------------------------------
    if (tid < 64) {
        float2 pv = *(const float2*)&prod_lds[tid * 2];
        float s = pv.x + pv.y;
#pragma unroll
        for (int m = 32; m; m >>= 1) s += __shfl_xor(s, m);
        if (tid == 0) out[base + 510] = sigf(s);
    }
    if (tid == 0) out[base + 511] = 0.0f;
}

// ---------------------------------------------------------------------------
extern "C" void kernel_launch(void* const* d_in, const int* in_sizes, int n_in,
                              void* d_out, int out_size, void* d_ws, size_t ws_size,
                              hipStream_t stream) {
    const int*   q_seq    = (const int*)d_in[0];
    const int*   c_seq    = (const int*)d_in[1];
    const int*   qd_seq   = (const int*)d_in[2];
    const int*   cd_seq   = (const int*)d_in[3];
    const int*   corr_seq = (const int*)d_in[4];
    const float* E_q    = (const float*)d_in[5];
    const float* E_c    = (const float*)d_in[6];
    const float* E_qd   = (const float*)d_in[7];
    const float* E_cd   = (const float*)d_in[8];
    const float* E_corr = (const float*)d_in[9];
    const float* Wx     = (const float*)d_in[10];
    const float* bx     = (const float*)d_in[11];
    const float* W_s1   = (const float*)d_in[12];
    const float* b_s1   = (const float*)d_in[13];
    const float* W_s2   = (const float*)d_in[14];
    const float* b_s2   = (const float*)d_in[15];
    const float* W_p1   = (const float*)d_in[16];
    const float* b_p1   = (const float*)d_in[17];
    const float* W_p2   = (const float*)d_in[18];
    const float* b_p2   = (const float*)d_in[19];
    const float* W_ki   = (const float*)d_in[20];
    const float* b_ki   = (const float*)d_in[21];
    const float* h0     = (const float*)d_in[22];
    float* out = (float*)d_out;

    float* xbuf = (float*)d_ws;
    float* Ck   = xbuf + (size_t)BB * SS * DD;
    float* Cp1  = Ck  + 256;
    float* Cp2  = Cp1 + 256;
    float* Qk   = Cp2 + 256;
    float* Cdk  = Qk  + 101 * 128;

    dimkt_tables<<<208, 128, 0, stream>>>(E_corr, E_qd, E_cd, W_ki, W_p1, W_p2,
                                          b_ki, b_p1, b_p2, Ck, Cp1, Cp2, Qk, Cdk);

    dimkt_xgemm<<<(BB * SS) / 128, 256, 0, stream>>>(q_seq, c_seq, qd_seq, cd_seq,
                                                     E_q, E_c, E_qd, E_cd, Wx, bx, xbuf);

    dimkt_scan<<<BB, 512, 0, stream>>>(xbuf, corr_seq, qd_seq, cd_seq,
                                       W_s1, b_s1, W_s2, b_s2, W_p1, W_p2, W_ki,
                                       Ck, Cp1, Cp2, Qk, Cdk, h0, out);
}